// Round 14
// baseline (187.031 us; speedup 1.0000x reference)
//
#include <hip/hip_runtime.h>
#include <hip/hip_bf16.h>
#include <math.h>

// Problem constants
#define BB 2
#define CC 512
#define DD 512
#define HH 8
#define DH 64
#define TI 8     // i-rows per attn2 block

typedef __attribute__((ext_vector_type(8))) short short8;      // 8 bf16 (4 VGPRs)
typedef __attribute__((ext_vector_type(16))) float floatx16;   // MFMA 32x32 acc
typedef __attribute__((ext_vector_type(2))) float float2v;     // packed fp32 pair
typedef unsigned short u16;

__device__ __forceinline__ float fast_rcp(float x) {
#if __has_builtin(__builtin_amdgcn_rcpf)
    return __builtin_amdgcn_rcpf(x);
#else
    return 1.0f / x;
#endif
}

// HW-packed fp32x2 -> bf16x2 (v_cvt_pk_bf16_f32 on gfx950, RNE). a in low half.
__device__ __forceinline__ unsigned pk_bf16(float a, float b) {
    __hip_bfloat162 h2 = __float22bfloat162_rn(make_float2(a, b));
    unsigned r;
    __builtin_memcpy(&r, &h2, 4);
    return r;
}

__device__ __forceinline__ short8 mk_short8(unsigned u0, unsigned u1,
                                            unsigned u2, unsigned u3) {
    uint4 u = make_uint4(u0, u1, u2, u3);
    short8 r;
    __builtin_memcpy(&r, &u, 16);
    return r;
}

__device__ __forceinline__ float2v pkfma(float2v a, float2v b, float2v c) {
#if __has_builtin(__builtin_elementwise_fma)
    return __builtin_elementwise_fma(a, b, c);
#else
    float2v r; r[0] = fmaf(a[0], b[0], c[0]); r[1] = fmaf(a[1], b[1], c[1]);
    return r;
#endif
}

// split 8 consecutive floats into packed bf16 hi / lo (Markidis split)
__device__ __forceinline__ void split_pack(const float* src, unsigned* hpk, unsigned* lpk) {
    #pragma unroll
    for (int p = 0; p < 4; ++p) {
        float a = src[2 * p], b = src[2 * p + 1];
        unsigned hp = pk_bf16(a, b);
        float la = a - __uint_as_float(hp << 16);
        float lb = b - __uint_as_float(hp & 0xffff0000u);
        hpk[p] = hp;
        lpk[p] = pk_bf16(la, lb);
    }
}

// gelu(h) = 0.5h + s*Q(s), s=h^2; 2-term Q (validated r9-r13).
#define GC0 0.3989422804f
#define GC1 (-0.0664903801f)

__device__ __forceinline__ float2v gelu_dot2(float2v h, float2v w2, float2v p) {
    float2v s = h * h;
    float2v q = pkfma(s, float2v{GC1, GC1}, float2v{GC0, GC0});
    float2v t = s * q;
    float2v g = pkfma(h, float2v{0.5f, 0.5f}, t);
    return pkfma(g, w2, p);
}

// ---------------------------------------------------------------------------
// prep: one-time weight transforms (unchanged from r9).
// ---------------------------------------------------------------------------
__global__ __launch_bounds__(256) void prep(
    const float* __restrict__ Wq, const float* __restrict__ Wk,
    const float* __restrict__ Wv, const float* __restrict__ Wo,
    const float* __restrict__ W1, const float* __restrict__ b1,
    const float* __restrict__ bq,
    u16* __restrict__ wth, u16* __restrict__ wtl,
    u16* __restrict__ woh, u16* __restrict__ wol,
    float* __restrict__ b1p)
{
    __shared__ float SH[3 * 64 * 68];
    int j = blockIdx.x, t = threadIdx.x;
    if (j < 256) {
        int mat = j >> 6;
        const float* W = (mat == 0) ? Wq : (mat == 1) ? Wk : (mat == 2) ? Wv : Wo;
        u16* oh = (mat < 3) ? wth + (size_t)mat * 262144 : woh;
        u16* ol = (mat < 3) ? wtl + (size_t)mat * 262144 : wol;
        int tile = j & 63;
        int k0 = (tile >> 3) * 64, n0 = (tile & 7) * 64;
        float (*TT)[68] = (float(*)[68])SH;
        int r = t >> 4, c4 = (t & 15) * 4;
        #pragma unroll
        for (int rr = 0; rr < 4; ++rr) {
            int k = r + rr * 16;
            float4 v = *(const float4*)&W[(size_t)(k0 + k) * 512 + n0 + c4];
            TT[c4 + 0][k] = v.x; TT[c4 + 1][k] = v.y;
            TT[c4 + 2][k] = v.z; TT[c4 + 3][k] = v.w;
        }
        __syncthreads();
        int n = t >> 2, kc = (t & 3) * 16;
        #pragma unroll
        for (int g = 0; g < 2; ++g) {
            unsigned hpk[4], lpk[4];
            split_pack(&TT[n][kc + g * 8], hpk, lpk);
            *(uint4*)&oh[(size_t)(n0 + n) * 512 + k0 + kc + g * 8] =
                make_uint4(hpk[0], hpk[1], hpk[2], hpk[3]);
            *(uint4*)&ol[(size_t)(n0 + n) * 512 + k0 + kc + g * 8] =
                make_uint4(lpk[0], lpk[1], lpk[2], lpk[3]);
        }
    } else if (j < 320) {
        int jj = j - 256;
        int D0 = (jj >> 3) * 64, h = jj & 7;
        float (*WQ)[68]  = (float(*)[68])SH;
        float (*W1Q)[68] = (float(*)[68])(SH + 64 * 68);
        float (*OT)[68]  = (float(*)[68])(SH + 2 * 64 * 68);
        int r = t >> 4, c4 = (t & 15) * 4;
        #pragma unroll
        for (int rr = 0; rr < 4; ++rr) {
            int d = r + rr * 16;
            *(float4*)&WQ[d][c4]  = *(const float4*)&Wq[(size_t)(D0 + d) * 512 + h * 64 + c4];
            *(float4*)&W1Q[d][c4] = *(const float4*)&W1[(size_t)d * 64 + c4];
        }
        __syncthreads();
        int D = t & 63, ec = (t >> 6) * 16;
        float outv[16];
        #pragma unroll
        for (int i = 0; i < 16; ++i) outv[i] = 0.0f;
        for (int d4 = 0; d4 < 16; ++d4) {
            float4 wq4 = *(float4*)&WQ[D][d4 * 4];
            float wqa[4] = {wq4.x, wq4.y, wq4.z, wq4.w};
            #pragma unroll
            for (int dd = 0; dd < 4; ++dd) {
                float wv_ = wqa[dd];
                const float* wrow = &W1Q[d4 * 4 + dd][ec];
                #pragma unroll
                for (int i = 0; i < 16; ++i) outv[i] = fmaf(wv_, wrow[i], outv[i]);
            }
        }
        #pragma unroll
        for (int i = 0; i < 16; ++i) OT[ec + i][D] = outv[i];
        __syncthreads();
        int n = t >> 2, kc = (t & 3) * 16;
        u16* oh3 = wth + (size_t)3 * 262144;
        u16* ol3 = wtl + (size_t)3 * 262144;
        #pragma unroll
        for (int g = 0; g < 2; ++g) {
            unsigned hpk[4], lpk[4];
            split_pack(&OT[n][kc + g * 8], hpk, lpk);
            *(uint4*)&oh3[(size_t)(h * 64 + n) * 512 + D0 + kc + g * 8] =
                make_uint4(hpk[0], hpk[1], hpk[2], hpk[3]);
            *(uint4*)&ol3[(size_t)(h * 64 + n) * 512 + D0 + kc + g * 8] =
                make_uint4(lpk[0], lpk[1], lpk[2], lpk[3]);
        }
    } else {
        for (int n = t; n < 512; n += 256) {
            int h = n >> 6, e = n & 63;
            float s = b1[e];
            for (int d = 0; d < 64; ++d)
                s = fmaf(bq[h * 64 + d], W1[(size_t)d * 64 + e], s);
            b1p[n] = s;
        }
    }
}

// ---------------------------------------------------------------------------
// gemm_qkv: [q|k|v|hqc] = x @ WT^T + bias.
// R14: asymmetric split -- A (x) bf16-hi only, B (weights) hi+lo ->
// 2 MFMA/k-step, 3 LDS arrays (24 KB). x-lo term dropped: adds rel ~2^-9 on
// q/k/v/hqc, at/below the bf16 rounding attn2 already applies (r13 evidence:
// pure-bf16 vf passed with absmax unchanged).
// v blocks (mat==2) also emit v bf16 B-fragments (vf) for MFMA-PV.
// ---------------------------------------------------------------------------
__global__ __launch_bounds__(256) void gemm_qkv(
    const float* __restrict__ x,
    const u16* __restrict__ wth, const u16* __restrict__ wtl,
    const float* __restrict__ bq, const float* __restrict__ bk,
    const float* __restrict__ bv, const float* __restrict__ b1p,
    float* __restrict__ qw, float* __restrict__ kw, float* __restrict__ vw,
    float* __restrict__ hqc, u16* __restrict__ vf)
{
    __shared__ u16 Ah[64][64], Bh[64][64], Bl[64][64];  // 24 KB
    int t = threadIdx.x;
    int m0 = blockIdx.x * 64;
    int ny = blockIdx.y;
    int mat = ny >> 3, n0 = (ny & 7) * 64;
    const u16* WH = wth + (size_t)mat * 262144;
    const u16* WL = wtl + (size_t)mat * 262144;
    const float* bias = (mat == 0) ? bq : (mat == 1) ? bk : (mat == 2) ? bv : b1p;
    float* out = (mat == 0) ? qw : (mat == 1) ? kw : (mat == 2) ? vw : hqc;

    int lane = t & 63, w = t >> 6;
    int mrow = (w & 1) * 32, ncol = (w >> 1) * 32;
    int col = lane & 31, half = lane >> 5;
    int sr = t >> 2, skc = (t & 3) * 16;

    floatx16 acc = {0.0f,0.0f,0.0f,0.0f,0.0f,0.0f,0.0f,0.0f,
                    0.0f,0.0f,0.0f,0.0f,0.0f,0.0f,0.0f,0.0f};

    for (int k0 = 0; k0 < 512; k0 += 64) {
        float xa[16];
        const float* xr = &x[(size_t)(m0 + sr) * 512 + k0 + skc];
        *(float4*)&xa[0]  = *(const float4*)&xr[0];
        *(float4*)&xa[4]  = *(const float4*)&xr[4];
        *(float4*)&xa[8]  = *(const float4*)&xr[8];
        *(float4*)&xa[12] = *(const float4*)&xr[12];
        #pragma unroll
        for (int g = 0; g < 2; ++g) {
            unsigned hpk[4];
            #pragma unroll
            for (int p = 0; p < 4; ++p)
                hpk[p] = pk_bf16(xa[g * 8 + 2 * p], xa[g * 8 + 2 * p + 1]);
            int gg = (skc >> 3) + g;
            int sw = (gg ^ (sr & 7)) * 8;
            *(uint4*)&Ah[sr][sw] = make_uint4(hpk[0], hpk[1], hpk[2], hpk[3]);
            *(uint4*)&Bh[sr][sw] = *(const uint4*)&WH[(size_t)(n0 + sr) * 512 + k0 + skc + g * 8];
            *(uint4*)&Bl[sr][sw] = *(const uint4*)&WL[(size_t)(n0 + sr) * 512 + k0 + skc + g * 8];
        }
        __syncthreads();
        int ar = mrow + col, br = ncol + col;
        #pragma unroll
        for (int kk = 0; kk < 4; ++kk) {
            int g8 = kk * 2 + half;
            short8 ah = *(short8*)&Ah[ar][(g8 ^ (ar & 7)) * 8];
            short8 bh = *(short8*)&Bh[br][(g8 ^ (br & 7)) * 8];
            short8 bl = *(short8*)&Bl[br][(g8 ^ (br & 7)) * 8];
            acc = __builtin_amdgcn_mfma_f32_32x32x16_bf16(ah, bl, acc, 0, 0, 0);
            acc = __builtin_amdgcn_mfma_f32_32x32x16_bf16(ah, bh, acc, 0, 0, 0);
        }
        __syncthreads();
    }
    int h = n0 >> 6;
    int e = ncol + col;
    float bv_ = bias[n0 + e];
    #pragma unroll
    for (int reg = 0; reg < 16; ++reg) {
        int r = m0 + mrow + (reg & 3) + 8 * (reg >> 2) + 4 * half;
        int b = r >> 9, c = r & 511;
        out[((size_t)(b * HH + h) * CC + c) * DH + e] = acc[reg] + bv_;
    }
    if (mat == 2) {
        // emit v bf16 fragments for MFMA-PV
        #pragma unroll
        for (int reg = 0; reg < 16; ++reg) {
            int r = m0 + mrow + (reg & 3) + 8 * (reg >> 2) + 4 * half;
            int b = r >> 9, c = r & 511;
            int bh2 = b * HH + h;
            u16 val = (u16)(pk_bf16(acc[reg] + bv_, 0.0f) & 0xffffu);
            vf[((((size_t)bh2 * 32 + (c >> 4)) * 2 + ((c >> 3) & 1)) * 64 + e) * 8
               + (c & 7)] = val;
        }
    }
}

// ---------------------------------------------------------------------------
// gemm_out: y = reshape(ow) @ Wo + bo.
// R14: asymmetric split (A = ow bf16-hi only, B hi+lo) -- 2 MFMA/k-step.
// ---------------------------------------------------------------------------
__global__ __launch_bounds__(256) void gemm_out(
    const float* __restrict__ ow,
    const u16* __restrict__ woh, const u16* __restrict__ wol,
    const float* __restrict__ bo, float* __restrict__ y)
{
    __shared__ u16 Ah[64][64], Bh[64][64], Bl[64][64];  // 24 KB
    int t = threadIdx.x;
    int m0 = blockIdx.x * 64, n0 = blockIdx.y * 64;
    int lane = t & 63, w = t >> 6;
    int mrow = (w & 1) * 32, ncol = (w >> 1) * 32;
    int col = lane & 31, half = lane >> 5;
    int sr = t >> 2, skc = (t & 3) * 16;

    floatx16 acc = {0.0f,0.0f,0.0f,0.0f,0.0f,0.0f,0.0f,0.0f,
                    0.0f,0.0f,0.0f,0.0f,0.0f,0.0f,0.0f,0.0f};
    int r = m0 + sr, b = r >> 9, c = r & 511;

    for (int k0 = 0; k0 < 512; k0 += 64) {
        int hh = k0 >> 6;
        float xa[16];
        const float* arow = &ow[((size_t)(b * HH + hh) * CC + c) * DH + skc];
        *(float4*)&xa[0]  = *(const float4*)&arow[0];
        *(float4*)&xa[4]  = *(const float4*)&arow[4];
        *(float4*)&xa[8]  = *(const float4*)&arow[8];
        *(float4*)&xa[12] = *(const float4*)&arow[12];
        #pragma unroll
        for (int g = 0; g < 2; ++g) {
            unsigned hpk[4];
            #pragma unroll
            for (int p = 0; p < 4; ++p)
                hpk[p] = pk_bf16(xa[g * 8 + 2 * p], xa[g * 8 + 2 * p + 1]);
            int gg = (skc >> 3) + g;
            int sw = (gg ^ (sr & 7)) * 8;
            *(uint4*)&Ah[sr][sw] = make_uint4(hpk[0], hpk[1], hpk[2], hpk[3]);
            *(uint4*)&Bh[sr][sw] = *(const uint4*)&woh[(size_t)(n0 + sr) * 512 + k0 + skc + g * 8];
            *(uint4*)&Bl[sr][sw] = *(const uint4*)&wol[(size_t)(n0 + sr) * 512 + k0 + skc + g * 8];
        }
        __syncthreads();
        int ar = mrow + col, br = ncol + col;
        #pragma unroll
        for (int kk = 0; kk < 4; ++kk) {
            int g8 = kk * 2 + half;
            short8 ah = *(short8*)&Ah[ar][(g8 ^ (ar & 7)) * 8];
            short8 bh = *(short8*)&Bh[br][(g8 ^ (br & 7)) * 8];
            short8 bl = *(short8*)&Bl[br][(g8 ^ (br & 7)) * 8];
            acc = __builtin_amdgcn_mfma_f32_32x32x16_bf16(ah, bl, acc, 0, 0, 0);
            acc = __builtin_amdgcn_mfma_f32_32x32x16_bf16(ah, bh, acc, 0, 0, 0);
        }
        __syncthreads();
    }
    float bv_ = bo[n0 + ncol + col];
    #pragma unroll
    for (int reg = 0; reg < 16; ++reg) {
        int r2 = m0 + mrow + (reg & 3) + 8 * (reg >> 2) + 4 * half;
        y[(size_t)r2 * 512 + n0 + ncol + col] = acc[reg] + bv_;
    }
}

// ---------------------------------------------------------------------------
// attn2: MFMA second-order core (unchanged from r13).
// ---------------------------------------------------------------------------
__global__ __launch_bounds__(256, 2) void attn2(
    const float* qw, const float* __restrict__ kw,
    const float* __restrict__ hqc, const u16* __restrict__ vf,
    const float* __restrict__ W1, const float* __restrict__ W2,
    const float* __restrict__ b2p,
    float* ow)
{
    __shared__ u16 Alds[2][64][64];         // A_i bf16 dbuf        16 KB
    __shared__ u16 sc16[TI][512];           // raw scores bf16       8 KB

    int t = threadIdx.x;
    int lane = t & 63;
    int w = t >> 6;
    int h = lane >> 5;
    int col = lane & 31;

    int bid = blockIdx.x;
    int bh = ((bid & 7) << 1) | (bid >> 9);        // 0..15
    int i0 = ((bid >> 3) & 63) * TI;

    const float* qb  = qw  + ((size_t)bh * CC + i0) * DH;
    const float* hb  = hqc + ((size_t)bh * CC + i0) * DH;
    const float* kb  = kw  + (size_t)bh * CC * DH;
    const u16*   vfb = vf  + (size_t)bh * 32768;   // [32][2][64][8]

    float w1i_r[16], w1k_r[16];
    {
        int dbase = w * 16;
        #pragma unroll
        for (int dd = 0; dd < 16; ++dd) {
            w1i_r[dd] = W1[(size_t)(128 + dbase + dd) * 64 + lane];
            w1k_r[dd] = W1[(size_t)(64 + dbase + dd) * 64 + lane];
        }
    }

    short8 bfrag[4][4];
    for (int n = 0; n < 4; ++n) {
        int j = w * 128 + n * 32 + col;
        const float* kr = kb + (size_t)j * 64;
        #pragma unroll
        for (int kk = 0; kk < 4; ++kk) {
            int d = kk * 16 + h * 8;
            float4 k0 = *(const float4*)(kr + d);
            float4 k1 = *(const float4*)(kr + d + 4);
            bfrag[n][kk] = mk_short8(pk_bf16(k0.x, k0.y), pk_bf16(k0.z, k0.w),
                                     pk_bf16(k1.x, k1.y), pk_bf16(k1.z, k1.w));
        }
    }

    float2v w2p[2][8];
    #pragma unroll
    for (int m = 0; m < 2; ++m)
        #pragma unroll
        for (int gq = 0; gq < 8; ++gq) {
            int e = m * 32 + (gq >> 1) * 8 + h * 4 + (gq & 1) * 2;
            w2p[m][gq] = float2v{W2[e], W2[e + 1]};
        }

    #define PRODUCE_A(ii, buf)                                                  \
    {                                                                           \
        int e = lane;                                                           \
        int sw = e & 7;                                                         \
        _Pragma("unroll")                                                       \
        for (int gg = 0; gg < 2; ++gg) {                                        \
            int g8 = w * 2 + gg;                                                \
            const float* qr = qb + (ii) * 64 + g8 * 8;                          \
            float4 q0 = *(const float4*)qr;                                     \
            float4 q1 = *(const float4*)(qr + 4);                               \
            float qv[8] = {q0.x, q0.y, q0.z, q0.w, q1.x, q1.y, q1.z, q1.w};     \
            unsigned int pk[4];                                                 \
            _Pragma("unroll")                                                   \
            for (int p2 = 0; p2 < 4; ++p2) {                                    \
                float a0 = fmaf(qv[2 * p2 + 0], w1i_r[gg * 8 + 2 * p2 + 0],     \
                                w1k_r[gg * 8 + 2 * p2 + 0]);                    \
                float a1 = fmaf(qv[2 * p2 + 1], w1i_r[gg * 8 + 2 * p2 + 1],     \
                                w1k_r[gg * 8 + 2 * p2 + 1]);                    \
                pk[p2] = pk_bf16(a0, a1);                                       \
            }                                                                   \
            *(uint4*)&Alds[buf][e][(g8 ^ sw) * 8] =                             \
                make_uint4(pk[0], pk[1], pk[2], pk[3]);                         \
        }                                                                       \
    }

    PRODUCE_A(0, 0);
    __syncthreads();

    for (int ii = 0; ii < TI; ++ii) {
        int cur = ii & 1;

        short8 afrag[2][4];
        #pragma unroll
        for (int m = 0; m < 2; ++m) {
            int e = m * 32 + col;
            int sw = e & 7;
            #pragma unroll
            for (int kk = 0; kk < 4; ++kk) {
                int g8 = kk * 2 + h;
                afrag[m][kk] = *(short8*)&Alds[cur][e][(g8 ^ sw) * 8];
            }
        }
        floatx16 csx[2];
        #pragma unroll
        for (int m = 0; m < 2; ++m)
            #pragma unroll
            for (int g = 0; g < 4; ++g) {
                float4 c4 = *(const float4*)&hb[ii * 64 + m * 32 + g * 8 + h * 4];
                csx[m][g * 4 + 0] = c4.x; csx[m][g * 4 + 1] = c4.y;
                csx[m][g * 4 + 2] = c4.z; csx[m][g * 4 + 3] = c4.w;
            }

        if (ii + 1 < TI) PRODUCE_A(ii + 1, cur ^ 1);

        #pragma unroll
        for (int n = 0; n < 4; ++n) {
            floatx16 acc[2];
            acc[0] = __builtin_amdgcn_mfma_f32_32x32x16_bf16(
                         afrag[0][0], bfrag[n][0], csx[0], 0, 0, 0);
            acc[1] = __builtin_amdgcn_mfma_f32_32x32x16_bf16(
                         afrag[1][0], bfrag[n][0], csx[1], 0, 0, 0);
            #pragma unroll
            for (int kk = 1; kk < 4; ++kk) {
                acc[0] = __builtin_amdgcn_mfma_f32_32x32x16_bf16(
                             afrag[0][kk], bfrag[n][kk], acc[0], 0, 0, 0);
                acc[1] = __builtin_amdgcn_mfma_f32_32x32x16_bf16(
                             afrag[1][kk], bfrag[n][kk], acc[1], 0, 0, 0);
            }
            float2v p2 = {0.0f, 0.0f};
            #pragma unroll
            for (int m = 0; m < 2; ++m)
                #pragma unroll
                for (int g = 0; g < 4; ++g)
                    #pragma unroll
                    for (int pr = 0; pr < 2; ++pr) {
                        float2v hvv = {acc[m][g * 4 + pr * 2],
                                       acc[m][g * 4 + pr * 2 + 1]};
                        p2 = gelu_dot2(hvv, w2p[m][g * 2 + pr], p2);
                    }
            float p = p2[0] + p2[1];
            p += __shfl_xor(p, 32);
            if (h == 0) sc16[ii][w * 128 + n * 32 + col] = (u16)pk_bf16(p, p);
        }
        __syncthreads();
    }
    #undef PRODUCE_A

    // --- softmax over j per i-row; scores = (raw + b2)/8 ---
    float* attn = (float*)Alds;          // [TI][512] fp32 = 16 KB exactly
    float b2v = b2p[0];
    for (int iirow = w; iirow < TI; iirow += 4) {
        float xv[8];
        float m = -1e30f;
        #pragma unroll
        for (int c = 0; c < 8; ++c) {
            float raw = __uint_as_float((unsigned)sc16[iirow][c * 64 + lane] << 16);
            xv[c] = (raw + b2v) * 0.125f;
            m = fmaxf(m, xv[c]);
        }
        #pragma unroll
        for (int o = 1; o < 64; o <<= 1) m = fmaxf(m, __shfl_xor(m, o));
        float s = 0.0f;
        #pragma unroll
        for (int c = 0; c < 8; ++c) { xv[c] = __expf(xv[c] - m); s += xv[c]; }
        #pragma unroll
        for (int o = 1; o < 64; o <<= 1) s += __shfl_xor(s, o);
        float r = fast_rcp(s);
        #pragma unroll
        for (int c = 0; c < 8; ++c) attn[iirow * 512 + c * 64 + lane] = xv[c] * r;
    }
    __syncthreads();

    // --- PV via MFMA (r13) ---
    {
        float* part = (float*)sc16;      // [w(4)][i(8)][e(64)] fp32, 8 KB
        floatx16 pacc[2];
        pacc[0] = {0.0f,0.0f,0.0f,0.0f,0.0f,0.0f,0.0f,0.0f,
                   0.0f,0.0f,0.0f,0.0f,0.0f,0.0f,0.0f,0.0f};
        pacc[1] = pacc[0];
        #pragma unroll
        for (int s = 0; s < 8; ++s) {
            int jg = w * 8 + s;
            short8 afr = {0, 0, 0, 0, 0, 0, 0, 0};
            if (col < TI) {
                const float* ar = &attn[col * 512 + jg * 16 + h * 8];
                float4 a0 = *(const float4*)ar;
                float4 a1 = *(const float4*)(ar + 4);
                afr = mk_short8(pk_bf16(a0.x, a0.y), pk_bf16(a0.z, a0.w),
                                pk_bf16(a1.x, a1.y), pk_bf16(a1.z, a1.w));
            }
            const u16* vrow = vfb + ((size_t)jg * 2 + h) * 512;   // [64][8]
            short8 b0 = *(const short8*)&vrow[(size_t)(col) * 8];
            short8 b1 = *(const short8*)&vrow[(size_t)(32 + col) * 8];
            pacc[0] = __builtin_amdgcn_mfma_f32_32x32x16_bf16(afr, b0, pacc[0], 0, 0, 0);
            pacc[1] = __builtin_amdgcn_mfma_f32_32x32x16_bf16(afr, b1, pacc[1], 0, 0, 0);
        }
        #pragma unroll
        for (int nt = 0; nt < 2; ++nt)
            #pragma unroll
            for (int reg = 0; reg < 4; ++reg) {
                int i = (reg & 3) + 4 * h;
                part[(w * 8 + i) * 64 + nt * 32 + col] = pacc[nt][reg];
            }
        __syncthreads();
        for (int idx = t; idx < 512; idx += 256) {
            int i = idx >> 6, e = idx & 63;
            float s = part[(0 + i) * 64 + e] + part[(8 + i) * 64 + e]
                    + part[(16 + i) * 64 + e] + part[(24 + i) * 64 + e];
            ow[((size_t)bh * CC + i0 + i) * DH + e] = s;
        }
    }
}

extern "C" void kernel_launch(void* const* d_in, const int* in_sizes, int n_in,
                              void* d_out, int out_size, void* d_ws, size_t ws_size,
                              hipStream_t stream)
{
    const float* x  = (const float*)d_in[0];
    const float* Wq = (const float*)d_in[1];
    const float* bq = (const float*)d_in[2];
    const float* Wk = (const float*)d_in[3];
    const float* bk = (const float*)d_in[4];
    const float* Wv = (const float*)d_in[5];
    const float* bv = (const float*)d_in[6];
    const float* W1 = (const float*)d_in[7];
    const float* b1 = (const float*)d_in[8];
    const float* W2 = (const float*)d_in[9];
    const float* b2 = (const float*)d_in[10];
    const float* Wo = (const float*)d_in[11];
    const float* bo = (const float*)d_in[12];
    float* y  = (float*)d_out;
    float* ws = (float*)d_ws;

    const size_t SEG = (size_t)BB * HH * CC * DH;  // 524288 floats
    float* qw  = ws;                 // also aliased as ow (disjoint lifetimes)
    float* kw  = ws + SEG;
    float* vw  = ws + 2 * SEG;
    float* hqc = ws + 3 * SEG;
    u16*   wth = (u16*)(ws + 4 * SEG);            // 4 x 512x512 bf16-hi
    u16*   wtl = (u16*)(ws + 5 * SEG);            // 4 x 512x512 bf16-lo
    u16*   woh = (u16*)(ws + 6 * SEG);            // Wo hi
    u16*   wol = (u16*)(ws + 6 * SEG + 131072);   // Wo lo
    float* b1p = ws + 6 * SEG + 262144;           // 512 floats
    u16*   vf  = (u16*)(ws + 6 * SEG + 262656);   // v frags: 512K u16 = 1 MB
    float* ow  = qw;                 // alias: q dead before ow written

    prep<<<dim3(321), 256, 0, stream>>>(Wq, Wk, Wv, Wo, W1, b1, bq,
                                        wth, wtl, woh, wol, b1p);
    gemm_qkv<<<dim3(16, 32), 256, 0, stream>>>(x, wth, wtl, bq, bk, bv, b1p,
                                               qw, kw, vw, hqc, vf);
    attn2<<<dim3(1024), 256, 0, stream>>>(qw, kw, hqc, vf, W1, W2, b2, ow);
    gemm_out<<<dim3(16, 8), 256, 0, stream>>>(ow, woh, wol, bo, y);
}

// Round 15
// 177.270 us; speedup vs baseline: 1.0551x; 1.0551x over previous
//
#include <hip/hip_runtime.h>
#include <hip/hip_bf16.h>
#include <math.h>

// Problem constants
#define BB 2
#define CC 512
#define DD 512
#define HH 8
#define DH 64
#define TI 8     // i-rows per attn2 block

typedef __attribute__((ext_vector_type(8))) short short8;      // 8 bf16 (4 VGPRs)
typedef __attribute__((ext_vector_type(16))) float floatx16;   // MFMA 32x32 acc
typedef __attribute__((ext_vector_type(2))) float float2v;     // packed fp32 pair
typedef unsigned short u16;

__device__ __forceinline__ float fast_rcp(float x) {
#if __has_builtin(__builtin_amdgcn_rcpf)
    return __builtin_amdgcn_rcpf(x);
#else
    return 1.0f / x;
#endif
}

// HW-packed fp32x2 -> bf16x2 (v_cvt_pk_bf16_f32 on gfx950, RNE). a in low half.
__device__ __forceinline__ unsigned pk_bf16(float a, float b) {
    __hip_bfloat162 h2 = __float22bfloat162_rn(make_float2(a, b));
    unsigned r;
    __builtin_memcpy(&r, &h2, 4);
    return r;
}

__device__ __forceinline__ short8 mk_short8(unsigned u0, unsigned u1,
                                            unsigned u2, unsigned u3) {
    uint4 u = make_uint4(u0, u1, u2, u3);
    short8 r;
    __builtin_memcpy(&r, &u, 16);
    return r;
}

__device__ __forceinline__ float2v pkfma(float2v a, float2v b, float2v c) {
#if __has_builtin(__builtin_elementwise_fma)
    return __builtin_elementwise_fma(a, b, c);
#else
    float2v r; r[0] = fmaf(a[0], b[0], c[0]); r[1] = fmaf(a[1], b[1], c[1]);
    return r;
#endif
}

// split 8 consecutive floats into packed bf16 hi / lo (Markidis split)
__device__ __forceinline__ void split_pack(const float* src, unsigned* hpk, unsigned* lpk) {
    #pragma unroll
    for (int p = 0; p < 4; ++p) {
        float a = src[2 * p], b = src[2 * p + 1];
        unsigned hp = pk_bf16(a, b);
        float la = a - __uint_as_float(hp << 16);
        float lb = b - __uint_as_float(hp & 0xffff0000u);
        hpk[p] = hp;
        lpk[p] = pk_bf16(la, lb);
    }
}

// gelu(h) = 0.5h + s*Q(s), s=h^2; 2-term Q (validated r9-r14).
#define GC0 0.3989422804f
#define GC1 (-0.0664903801f)

__device__ __forceinline__ float2v gelu_dot2(float2v h, float2v w2, float2v p) {
    float2v s = h * h;
    float2v q = pkfma(s, float2v{GC1, GC1}, float2v{GC0, GC0});
    float2v t = s * q;
    float2v g = pkfma(h, float2v{0.5f, 0.5f}, t);
    return pkfma(g, w2, p);
}

// ---------------------------------------------------------------------------
// prep: one-time weight transforms (unchanged from r9).
// ---------------------------------------------------------------------------
__global__ __launch_bounds__(256) void prep(
    const float* __restrict__ Wq, const float* __restrict__ Wk,
    const float* __restrict__ Wv, const float* __restrict__ Wo,
    const float* __restrict__ W1, const float* __restrict__ b1,
    const float* __restrict__ bq,
    u16* __restrict__ wth, u16* __restrict__ wtl,
    u16* __restrict__ woh, u16* __restrict__ wol,
    float* __restrict__ b1p)
{
    __shared__ float SH[3 * 64 * 68];
    int j = blockIdx.x, t = threadIdx.x;
    if (j < 256) {
        int mat = j >> 6;
        const float* W = (mat == 0) ? Wq : (mat == 1) ? Wk : (mat == 2) ? Wv : Wo;
        u16* oh = (mat < 3) ? wth + (size_t)mat * 262144 : woh;
        u16* ol = (mat < 3) ? wtl + (size_t)mat * 262144 : wol;
        int tile = j & 63;
        int k0 = (tile >> 3) * 64, n0 = (tile & 7) * 64;
        float (*TT)[68] = (float(*)[68])SH;
        int r = t >> 4, c4 = (t & 15) * 4;
        #pragma unroll
        for (int rr = 0; rr < 4; ++rr) {
            int k = r + rr * 16;
            float4 v = *(const float4*)&W[(size_t)(k0 + k) * 512 + n0 + c4];
            TT[c4 + 0][k] = v.x; TT[c4 + 1][k] = v.y;
            TT[c4 + 2][k] = v.z; TT[c4 + 3][k] = v.w;
        }
        __syncthreads();
        int n = t >> 2, kc = (t & 3) * 16;
        #pragma unroll
        for (int g = 0; g < 2; ++g) {
            unsigned hpk[4], lpk[4];
            split_pack(&TT[n][kc + g * 8], hpk, lpk);
            *(uint4*)&oh[(size_t)(n0 + n) * 512 + k0 + kc + g * 8] =
                make_uint4(hpk[0], hpk[1], hpk[2], hpk[3]);
            *(uint4*)&ol[(size_t)(n0 + n) * 512 + k0 + kc + g * 8] =
                make_uint4(lpk[0], lpk[1], lpk[2], lpk[3]);
        }
    } else if (j < 320) {
        int jj = j - 256;
        int D0 = (jj >> 3) * 64, h = jj & 7;
        float (*WQ)[68]  = (float(*)[68])SH;
        float (*W1Q)[68] = (float(*)[68])(SH + 64 * 68);
        float (*OT)[68]  = (float(*)[68])(SH + 2 * 64 * 68);
        int r = t >> 4, c4 = (t & 15) * 4;
        #pragma unroll
        for (int rr = 0; rr < 4; ++rr) {
            int d = r + rr * 16;
            *(float4*)&WQ[d][c4]  = *(const float4*)&Wq[(size_t)(D0 + d) * 512 + h * 64 + c4];
            *(float4*)&W1Q[d][c4] = *(const float4*)&W1[(size_t)d * 64 + c4];
        }
        __syncthreads();
        int D = t & 63, ec = (t >> 6) * 16;
        float outv[16];
        #pragma unroll
        for (int i = 0; i < 16; ++i) outv[i] = 0.0f;
        for (int d4 = 0; d4 < 16; ++d4) {
            float4 wq4 = *(float4*)&WQ[D][d4 * 4];
            float wqa[4] = {wq4.x, wq4.y, wq4.z, wq4.w};
            #pragma unroll
            for (int dd = 0; dd < 4; ++dd) {
                float wv_ = wqa[dd];
                const float* wrow = &W1Q[d4 * 4 + dd][ec];
                #pragma unroll
                for (int i = 0; i < 16; ++i) outv[i] = fmaf(wv_, wrow[i], outv[i]);
            }
        }
        #pragma unroll
        for (int i = 0; i < 16; ++i) OT[ec + i][D] = outv[i];
        __syncthreads();
        int n = t >> 2, kc = (t & 3) * 16;
        u16* oh3 = wth + (size_t)3 * 262144;
        u16* ol3 = wtl + (size_t)3 * 262144;
        #pragma unroll
        for (int g = 0; g < 2; ++g) {
            unsigned hpk[4], lpk[4];
            split_pack(&OT[n][kc + g * 8], hpk, lpk);
            *(uint4*)&oh3[(size_t)(h * 64 + n) * 512 + D0 + kc + g * 8] =
                make_uint4(hpk[0], hpk[1], hpk[2], hpk[3]);
            *(uint4*)&ol3[(size_t)(h * 64 + n) * 512 + D0 + kc + g * 8] =
                make_uint4(lpk[0], lpk[1], lpk[2], lpk[3]);
        }
    } else {
        for (int n = t; n < 512; n += 256) {
            int h = n >> 6, e = n & 63;
            float s = b1[e];
            for (int d = 0; d < 64; ++d)
                s = fmaf(bq[h * 64 + d], W1[(size_t)d * 64 + e], s);
            b1p[n] = s;
        }
    }
}

// ---------------------------------------------------------------------------
// gemm_qkv: [q|k|v|hqc] = x @ WT^T + bias (asymmetric split, r14).
// R15: k blocks (mat==1) emit ONLY bf16 B-fragments kf[bh][kk(4)][hf(2)][j][b]
// (the fp32 kw store is dead); v blocks (mat==2) emit ONLY vf fragments.
// attn2 then loads both fragment sets with raw b128 reads (zero conversion).
// ---------------------------------------------------------------------------
__global__ __launch_bounds__(256) void gemm_qkv(
    const float* __restrict__ x,
    const u16* __restrict__ wth, const u16* __restrict__ wtl,
    const float* __restrict__ bq, const float* __restrict__ bk,
    const float* __restrict__ bv, const float* __restrict__ b1p,
    float* __restrict__ qw, float* __restrict__ hqc,
    u16* __restrict__ kf, u16* __restrict__ vf)
{
    __shared__ u16 Ah[64][64], Bh[64][64], Bl[64][64];  // 24 KB
    int t = threadIdx.x;
    int m0 = blockIdx.x * 64;
    int ny = blockIdx.y;
    int mat = ny >> 3, n0 = (ny & 7) * 64;
    const u16* WH = wth + (size_t)mat * 262144;
    const u16* WL = wtl + (size_t)mat * 262144;
    const float* bias = (mat == 0) ? bq : (mat == 1) ? bk : (mat == 2) ? bv : b1p;

    int lane = t & 63, w = t >> 6;
    int mrow = (w & 1) * 32, ncol = (w >> 1) * 32;
    int col = lane & 31, half = lane >> 5;
    int sr = t >> 2, skc = (t & 3) * 16;

    floatx16 acc = {0.0f,0.0f,0.0f,0.0f,0.0f,0.0f,0.0f,0.0f,
                    0.0f,0.0f,0.0f,0.0f,0.0f,0.0f,0.0f,0.0f};

    for (int k0 = 0; k0 < 512; k0 += 64) {
        float xa[16];
        const float* xr = &x[(size_t)(m0 + sr) * 512 + k0 + skc];
        *(float4*)&xa[0]  = *(const float4*)&xr[0];
        *(float4*)&xa[4]  = *(const float4*)&xr[4];
        *(float4*)&xa[8]  = *(const float4*)&xr[8];
        *(float4*)&xa[12] = *(const float4*)&xr[12];
        #pragma unroll
        for (int g = 0; g < 2; ++g) {
            unsigned hpk[4];
            #pragma unroll
            for (int p = 0; p < 4; ++p)
                hpk[p] = pk_bf16(xa[g * 8 + 2 * p], xa[g * 8 + 2 * p + 1]);
            int gg = (skc >> 3) + g;
            int sw = (gg ^ (sr & 7)) * 8;
            *(uint4*)&Ah[sr][sw] = make_uint4(hpk[0], hpk[1], hpk[2], hpk[3]);
            *(uint4*)&Bh[sr][sw] = *(const uint4*)&WH[(size_t)(n0 + sr) * 512 + k0 + skc + g * 8];
            *(uint4*)&Bl[sr][sw] = *(const uint4*)&WL[(size_t)(n0 + sr) * 512 + k0 + skc + g * 8];
        }
        __syncthreads();
        int ar = mrow + col, br = ncol + col;
        #pragma unroll
        for (int kk = 0; kk < 4; ++kk) {
            int g8 = kk * 2 + half;
            short8 ah = *(short8*)&Ah[ar][(g8 ^ (ar & 7)) * 8];
            short8 bh = *(short8*)&Bh[br][(g8 ^ (br & 7)) * 8];
            short8 bl = *(short8*)&Bl[br][(g8 ^ (br & 7)) * 8];
            acc = __builtin_amdgcn_mfma_f32_32x32x16_bf16(ah, bl, acc, 0, 0, 0);
            acc = __builtin_amdgcn_mfma_f32_32x32x16_bf16(ah, bh, acc, 0, 0, 0);
        }
        __syncthreads();
    }
    int h = n0 >> 6;
    int e = ncol + col;
    float bv_ = bias[n0 + e];
    if (mat == 0 || mat == 3) {
        float* out = (mat == 0) ? qw : hqc;
        #pragma unroll
        for (int reg = 0; reg < 16; ++reg) {
            int r = m0 + mrow + (reg & 3) + 8 * (reg >> 2) + 4 * half;
            int b = r >> 9, c = r & 511;
            out[((size_t)(b * HH + h) * CC + c) * DH + e] = acc[reg] + bv_;
        }
    } else if (mat == 1) {
        // k B-fragments: kf[((bh*4 + d>>4)*2 + (d>>3)&1)*512 + j]*8 + (d&7)
        int d = e;
        #pragma unroll
        for (int reg = 0; reg < 16; ++reg) {
            int r = m0 + mrow + (reg & 3) + 8 * (reg >> 2) + 4 * half;
            int b = r >> 9, c = r & 511;            // c = j
            int bh2 = b * HH + h;
            u16 val = (u16)(pk_bf16(acc[reg] + bv_, 0.0f) & 0xffffu);
            kf[((((size_t)bh2 * 4 + (d >> 4)) * 2 + ((d >> 3) & 1)) * 512 + c) * 8
               + (d & 7)] = val;
        }
    } else {
        // v B-fragments: vf[((bh*32 + j>>4)*2 + (j>>3)&1)*64 + e]*8 + (j&7)
        #pragma unroll
        for (int reg = 0; reg < 16; ++reg) {
            int r = m0 + mrow + (reg & 3) + 8 * (reg >> 2) + 4 * half;
            int b = r >> 9, c = r & 511;            // c = j
            int bh2 = b * HH + h;
            u16 val = (u16)(pk_bf16(acc[reg] + bv_, 0.0f) & 0xffffu);
            vf[((((size_t)bh2 * 32 + (c >> 4)) * 2 + ((c >> 3) & 1)) * 64 + e) * 8
               + (c & 7)] = val;
        }
    }
}

// ---------------------------------------------------------------------------
// gemm_out: y = reshape(ow) @ Wo + bo (asymmetric split, r14).
// ---------------------------------------------------------------------------
__global__ __launch_bounds__(256) void gemm_out(
    const float* __restrict__ ow,
    const u16* __restrict__ woh, const u16* __restrict__ wol,
    const float* __restrict__ bo, float* __restrict__ y)
{
    __shared__ u16 Ah[64][64], Bh[64][64], Bl[64][64];  // 24 KB
    int t = threadIdx.x;
    int m0 = blockIdx.x * 64, n0 = blockIdx.y * 64;
    int lane = t & 63, w = t >> 6;
    int mrow = (w & 1) * 32, ncol = (w >> 1) * 32;
    int col = lane & 31, half = lane >> 5;
    int sr = t >> 2, skc = (t & 3) * 16;

    floatx16 acc = {0.0f,0.0f,0.0f,0.0f,0.0f,0.0f,0.0f,0.0f,
                    0.0f,0.0f,0.0f,0.0f,0.0f,0.0f,0.0f,0.0f};
    int r = m0 + sr, b = r >> 9, c = r & 511;

    for (int k0 = 0; k0 < 512; k0 += 64) {
        int hh = k0 >> 6;
        float xa[16];
        const float* arow = &ow[((size_t)(b * HH + hh) * CC + c) * DH + skc];
        *(float4*)&xa[0]  = *(const float4*)&arow[0];
        *(float4*)&xa[4]  = *(const float4*)&arow[4];
        *(float4*)&xa[8]  = *(const float4*)&arow[8];
        *(float4*)&xa[12] = *(const float4*)&arow[12];
        #pragma unroll
        for (int g = 0; g < 2; ++g) {
            unsigned hpk[4];
            #pragma unroll
            for (int p = 0; p < 4; ++p)
                hpk[p] = pk_bf16(xa[g * 8 + 2 * p], xa[g * 8 + 2 * p + 1]);
            int gg = (skc >> 3) + g;
            int sw = (gg ^ (sr & 7)) * 8;
            *(uint4*)&Ah[sr][sw] = make_uint4(hpk[0], hpk[1], hpk[2], hpk[3]);
            *(uint4*)&Bh[sr][sw] = *(const uint4*)&woh[(size_t)(n0 + sr) * 512 + k0 + skc + g * 8];
            *(uint4*)&Bl[sr][sw] = *(const uint4*)&wol[(size_t)(n0 + sr) * 512 + k0 + skc + g * 8];
        }
        __syncthreads();
        int ar = mrow + col, br = ncol + col;
        #pragma unroll
        for (int kk = 0; kk < 4; ++kk) {
            int g8 = kk * 2 + half;
            short8 ah = *(short8*)&Ah[ar][(g8 ^ (ar & 7)) * 8];
            short8 bh = *(short8*)&Bh[br][(g8 ^ (br & 7)) * 8];
            short8 bl = *(short8*)&Bl[br][(g8 ^ (br & 7)) * 8];
            acc = __builtin_amdgcn_mfma_f32_32x32x16_bf16(ah, bl, acc, 0, 0, 0);
            acc = __builtin_amdgcn_mfma_f32_32x32x16_bf16(ah, bh, acc, 0, 0, 0);
        }
        __syncthreads();
    }
    float bv_ = bo[n0 + ncol + col];
    #pragma unroll
    for (int reg = 0; reg < 16; ++reg) {
        int r2 = m0 + mrow + (reg & 3) + 8 * (reg >> 2) + 4 * half;
        y[(size_t)r2 * 512 + n0 + ncol + col] = acc[reg] + bv_;
    }
}

// ---------------------------------------------------------------------------
// attn2: MFMA second-order core (r13 structure).
// R15: bfrag loaded directly from kf (16 coalesced b128 reads, zero VALU
// conversion) -- the k->bf16 rounding moved into gemm_qkv (bit-identical).
// ---------------------------------------------------------------------------
__global__ __launch_bounds__(256, 2) void attn2(
    const float* qw, const u16* __restrict__ kf,
    const float* __restrict__ hqc, const u16* __restrict__ vf,
    const float* __restrict__ W1, const float* __restrict__ W2,
    const float* __restrict__ b2p,
    float* ow)
{
    __shared__ u16 Alds[2][64][64];         // A_i bf16 dbuf        16 KB
    __shared__ u16 sc16[TI][512];           // raw scores bf16       8 KB

    int t = threadIdx.x;
    int lane = t & 63;
    int w = t >> 6;
    int h = lane >> 5;
    int col = lane & 31;

    int bid = blockIdx.x;
    int bh = ((bid & 7) << 1) | (bid >> 9);        // 0..15
    int i0 = ((bid >> 3) & 63) * TI;

    const float* qb  = qw  + ((size_t)bh * CC + i0) * DH;
    const float* hb  = hqc + ((size_t)bh * CC + i0) * DH;
    const u16*   kfb = kf  + (size_t)bh * 32768;   // [4][2][512][8]
    const u16*   vfb = vf  + (size_t)bh * 32768;   // [32][2][64][8]

    float w1i_r[16], w1k_r[16];
    {
        int dbase = w * 16;
        #pragma unroll
        for (int dd = 0; dd < 16; ++dd) {
            w1i_r[dd] = W1[(size_t)(128 + dbase + dd) * 64 + lane];
            w1k_r[dd] = W1[(size_t)(64 + dbase + dd) * 64 + lane];
        }
    }

    // B fragments (k bf16): raw b128 loads from kf, no conversion.
    short8 bfrag[4][4];
    #pragma unroll
    for (int n = 0; n < 4; ++n)
        #pragma unroll
        for (int kk = 0; kk < 4; ++kk)
            bfrag[n][kk] = *(const short8*)
                &kfb[(((size_t)kk * 2 + h) * 512 + w * 128 + n * 32 + col) * 8];

    float2v w2p[2][8];
    #pragma unroll
    for (int m = 0; m < 2; ++m)
        #pragma unroll
        for (int gq = 0; gq < 8; ++gq) {
            int e = m * 32 + (gq >> 1) * 8 + h * 4 + (gq & 1) * 2;
            w2p[m][gq] = float2v{W2[e], W2[e + 1]};
        }

    #define PRODUCE_A(ii, buf)                                                  \
    {                                                                           \
        int e = lane;                                                           \
        int sw = e & 7;                                                         \
        _Pragma("unroll")                                                       \
        for (int gg = 0; gg < 2; ++gg) {                                        \
            int g8 = w * 2 + gg;                                                \
            const float* qr = qb + (ii) * 64 + g8 * 8;                          \
            float4 q0 = *(const float4*)qr;                                     \
            float4 q1 = *(const float4*)(qr + 4);                               \
            float qv[8] = {q0.x, q0.y, q0.z, q0.w, q1.x, q1.y, q1.z, q1.w};     \
            unsigned int pk[4];                                                 \
            _Pragma("unroll")                                                   \
            for (int p2 = 0; p2 < 4; ++p2) {                                    \
                float a0 = fmaf(qv[2 * p2 + 0], w1i_r[gg * 8 + 2 * p2 + 0],     \
                                w1k_r[gg * 8 + 2 * p2 + 0]);                    \
                float a1 = fmaf(qv[2 * p2 + 1], w1i_r[gg * 8 + 2 * p2 + 1],     \
                                w1k_r[gg * 8 + 2 * p2 + 1]);                    \
                pk[p2] = pk_bf16(a0, a1);                                       \
            }                                                                   \
            *(uint4*)&Alds[buf][e][(g8 ^ sw) * 8] =                             \
                make_uint4(pk[0], pk[1], pk[2], pk[3]);                         \
        }                                                                       \
    }

    PRODUCE_A(0, 0);
    __syncthreads();

    for (int ii = 0; ii < TI; ++ii) {
        int cur = ii & 1;

        short8 afrag[2][4];
        #pragma unroll
        for (int m = 0; m < 2; ++m) {
            int e = m * 32 + col;
            int sw = e & 7;
            #pragma unroll
            for (int kk = 0; kk < 4; ++kk) {
                int g8 = kk * 2 + h;
                afrag[m][kk] = *(short8*)&Alds[cur][e][(g8 ^ sw) * 8];
            }
        }
        floatx16 csx[2];
        #pragma unroll
        for (int m = 0; m < 2; ++m)
            #pragma unroll
            for (int g = 0; g < 4; ++g) {
                float4 c4 = *(const float4*)&hb[ii * 64 + m * 32 + g * 8 + h * 4];
                csx[m][g * 4 + 0] = c4.x; csx[m][g * 4 + 1] = c4.y;
                csx[m][g * 4 + 2] = c4.z; csx[m][g * 4 + 3] = c4.w;
            }

        if (ii + 1 < TI) PRODUCE_A(ii + 1, cur ^ 1);

        #pragma unroll
        for (int n = 0; n < 4; ++n) {
            floatx16 acc[2];
            acc[0] = __builtin_amdgcn_mfma_f32_32x32x16_bf16(
                         afrag[0][0], bfrag[n][0], csx[0], 0, 0, 0);
            acc[1] = __builtin_amdgcn_mfma_f32_32x32x16_bf16(
                         afrag[1][0], bfrag[n][0], csx[1], 0, 0, 0);
            #pragma unroll
            for (int kk = 1; kk < 4; ++kk) {
                acc[0] = __builtin_amdgcn_mfma_f32_32x32x16_bf16(
                             afrag[0][kk], bfrag[n][kk], acc[0], 0, 0, 0);
                acc[1] = __builtin_amdgcn_mfma_f32_32x32x16_bf16(
                             afrag[1][kk], bfrag[n][kk], acc[1], 0, 0, 0);
            }
            float2v p2 = {0.0f, 0.0f};
            #pragma unroll
            for (int m = 0; m < 2; ++m)
                #pragma unroll
                for (int g = 0; g < 4; ++g)
                    #pragma unroll
                    for (int pr = 0; pr < 2; ++pr) {
                        float2v hvv = {acc[m][g * 4 + pr * 2],
                                       acc[m][g * 4 + pr * 2 + 1]};
                        p2 = gelu_dot2(hvv, w2p[m][g * 2 + pr], p2);
                    }
            float p = p2[0] + p2[1];
            p += __shfl_xor(p, 32);
            if (h == 0) sc16[ii][w * 128 + n * 32 + col] = (u16)pk_bf16(p, p);
        }
        __syncthreads();
    }
    #undef PRODUCE_A

    // --- softmax over j per i-row; scores = (raw + b2)/8 ---
    float* attn = (float*)Alds;          // [TI][512] fp32 = 16 KB exactly
    float b2v = b2p[0];
    for (int iirow = w; iirow < TI; iirow += 4) {
        float xv[8];
        float m = -1e30f;
        #pragma unroll
        for (int c = 0; c < 8; ++c) {
            float raw = __uint_as_float((unsigned)sc16[iirow][c * 64 + lane] << 16);
            xv[c] = (raw + b2v) * 0.125f;
            m = fmaxf(m, xv[c]);
        }
        #pragma unroll
        for (int o = 1; o < 64; o <<= 1) m = fmaxf(m, __shfl_xor(m, o));
        float s = 0.0f;
        #pragma unroll
        for (int c = 0; c < 8; ++c) { xv[c] = __expf(xv[c] - m); s += xv[c]; }
        #pragma unroll
        for (int o = 1; o < 64; o <<= 1) s += __shfl_xor(s, o);
        float r = fast_rcp(s);
        #pragma unroll
        for (int c = 0; c < 8; ++c) attn[iirow * 512 + c * 64 + lane] = xv[c] * r;
    }
    __syncthreads();

    // --- PV via MFMA (r13) ---
    {
        float* part = (float*)sc16;      // [w(4)][i(8)][e(64)] fp32, 8 KB
        floatx16 pacc[2];
        pacc[0] = {0.0f,0.0f,0.0f,0.0f,0.0f,0.0f,0.0f,0.0f,
                   0.0f,0.0f,0.0f,0.0f,0.0f,0.0f,0.0f,0.0f};
        pacc[1] = pacc[0];
        #pragma unroll
        for (int s = 0; s < 8; ++s) {
            int jg = w * 8 + s;
            short8 afr = {0, 0, 0, 0, 0, 0, 0, 0};
            if (col < TI) {
                const float* ar = &attn[col * 512 + jg * 16 + h * 8];
                float4 a0 = *(const float4*)ar;
                float4 a1 = *(const float4*)(ar + 4);
                afr = mk_short8(pk_bf16(a0.x, a0.y), pk_bf16(a0.z, a0.w),
                                pk_bf16(a1.x, a1.y), pk_bf16(a1.z, a1.w));
            }
            const u16* vrow = vfb + ((size_t)jg * 2 + h) * 512;   // [64][8]
            short8 b0 = *(const short8*)&vrow[(size_t)(col) * 8];
            short8 b1 = *(const short8*)&vrow[(size_t)(32 + col) * 8];
            pacc[0] = __builtin_amdgcn_mfma_f32_32x32x16_bf16(afr, b0, pacc[0], 0, 0, 0);
            pacc[1] = __builtin_amdgcn_mfma_f32_32x32x16_bf16(afr, b1, pacc[1], 0, 0, 0);
        }
        #pragma unroll
        for (int nt = 0; nt < 2; ++nt)
            #pragma unroll
            for (int reg = 0; reg < 4; ++reg) {
                int i = (reg & 3) + 4 * h;
                part[(w * 8 + i) * 64 + nt * 32 + col] = pacc[nt][reg];
            }
        __syncthreads();
        for (int idx = t; idx < 512; idx += 256) {
            int i = idx >> 6, e = idx & 63;
            float s = part[(0 + i) * 64 + e] + part[(8 + i) * 64 + e]
                    + part[(16 + i) * 64 + e] + part[(24 + i) * 64 + e];
            ow[((size_t)bh * CC + i0 + i) * DH + e] = s;
        }
    }
}

extern "C" void kernel_launch(void* const* d_in, const int* in_sizes, int n_in,
                              void* d_out, int out_size, void* d_ws, size_t ws_size,
                              hipStream_t stream)
{
    const float* x  = (const float*)d_in[0];
    const float* Wq = (const float*)d_in[1];
    const float* bq = (const float*)d_in[2];
    const float* Wk = (const float*)d_in[3];
    const float* bk = (const float*)d_in[4];
    const float* Wv = (const float*)d_in[5];
    const float* bv = (const float*)d_in[6];
    const float* W1 = (const float*)d_in[7];
    const float* b1 = (const float*)d_in[8];
    const float* W2 = (const float*)d_in[9];
    const float* b2 = (const float*)d_in[10];
    const float* Wo = (const float*)d_in[11];
    const float* bo = (const float*)d_in[12];
    float* y  = (float*)d_out;
    float* ws = (float*)d_ws;

    const size_t SEG = (size_t)BB * HH * CC * DH;  // 524288 floats
    float* qw  = ws;                               // aliased as ow later
    float* hqc = ws + SEG;
    u16*   wth = (u16*)(ws + 2 * SEG);             // 4 x 512x512 bf16-hi (= SEG floats)
    u16*   wtl = (u16*)(ws + 3 * SEG);             // 4 x 512x512 bf16-lo
    u16*   woh = (u16*)(ws + 4 * SEG);             // Wo hi (131072 floats)
    u16*   wol = (u16*)(ws + 4 * SEG + 131072);    // Wo lo
    float* b1p = ws + 4 * SEG + 262144;            // 512 floats
    u16*   vf  = (u16*)(ws + 4 * SEG + 262656);    // 512K u16 (= 262144 floats)
    u16*   kf  = (u16*)(ws + 4 * SEG + 524800);    // 512K u16
    float* ow  = qw;                               // alias: q dead before ow written
    // total = 4*SEG + 786944 floats ~= 11.5 MB

    prep<<<dim3(321), 256, 0, stream>>>(Wq, Wk, Wv, Wo, W1, b1, bq,
                                        wth, wtl, woh, wol, b1p);
    gemm_qkv<<<dim3(16, 32), 256, 0, stream>>>(x, wth, wtl, bq, bk, bv, b1p,
                                               qw, hqc, kf, vf);
    attn2<<<dim3(1024), 256, 0, stream>>>(qw, kf, hqc, vf, W1, W2, b2, ow);
    gemm_out<<<dim3(16, 8), 256, 0, stream>>>(ow, woh, wol, bo, y);
}